// Round 12
// baseline (99.553 us; speedup 1.0000x reference)
//
#include <hip/hip_runtime.h>
#include <hip/hip_bf16.h>

#define N2V    34816
#define BATCH  2048
#define E1V    32768
#define KFAN   16
#define INDIM  128
#define HID    256
#define OUTD   128
#define E1TILES (E1V / 16)  // 2048

// ws layout (float32 units):
//   bs1   [256]        f32  @ 0
//   bs2   [128]        f32  @ 256
//   Wc1b  [256][256]   bf16 @ 384      (32768 f32 slots)
//   Wc2b  [128][512]   bf16 @ 33152    (32768 f32 slots)
//   agg1b [2048][256]  bf16 @ 65920    (262144 f32 slots)
//   h1s   [2048][256]  bf16 @ 328064   (262144 f32 slots)
#define OFF_BS1   0
#define OFF_BS2   256
#define OFF_WC1B  384
#define OFF_WC2B  33152
#define OFF_AGG1B 65920
#define OFF_H1S   328064

typedef __attribute__((ext_vector_type(8))) short bf16x8;
typedef __attribute__((ext_vector_type(4))) short short4v;
typedef __attribute__((ext_vector_type(4))) float f32x4;

__device__ __forceinline__ float bf2f(short u) {
  union { unsigned u32; float f; } cv;
  cv.u32 = ((unsigned)(unsigned short)u) << 16;
  return cv.f;
}

__device__ __forceinline__ short f2b(float f) {
  __hip_bfloat16 h = __float2bfloat16(f);
  return *reinterpret_cast<short*>(&h);
}

// K0: weight prepack (256 blocks x 256 thr).
__global__ __launch_bounds__(256) void prepack_kernel(
    const float* __restrict__ W1n, const float* __restrict__ b1n,
    const float* __restrict__ W1h, const float* __restrict__ b1h,
    const float* __restrict__ W2n, const float* __restrict__ b2n,
    const float* __restrict__ W2h, const float* __restrict__ b2h,
    __hip_bfloat16* __restrict__ Wc1b, __hip_bfloat16* __restrict__ Wc2b,
    float* __restrict__ bs1, float* __restrict__ bs2) {
  int idx = blockIdx.x * 256 + threadIdx.x;  // 0..65535
  int j1 = idx >> 8, c1 = idx & 255;
  float v1 = (c1 < 128) ? W1n[j1 * 128 + c1] : W1h[j1 * 128 + (c1 - 128)];
  Wc1b[idx] = __float2bfloat16(v1);
  int j2 = idx >> 9, c2 = idx & 511;
  float v2 = (c2 < 256) ? W2n[j2 * 256 + c2] : W2h[j2 * 256 + (c2 - 256)];
  Wc2b[idx] = __float2bfloat16(v2);
  if (idx < 256) bs1[idx] = b1n[idx] + b1h[idx];
  if (idx < 128) bs2[idx] = b2n[idx] + b2h[idx];
}

// MFMA + fused epilogue for one 16-row tile sitting in LDS buffer zb.
__device__ __forceinline__ void gemm_tile(
    const __hip_bfloat16* zb, int tile, int t,
    const short* __restrict__ wsrc, const float* __restrict__ bs1,
    __hip_bfloat16* __restrict__ agg1b, __hip_bfloat16* __restrict__ h1s) {
  const int wid = t >> 6;
  const int lane = t & 63;
  const int lr = lane & 15;
  const int lk8 = (lane >> 4) * 8;
  const int ncol0 = wid * 64;

  f32x4 acc[4];
#pragma unroll
  for (int n = 0; n < 4; ++n) acc[n] = (f32x4){0.f, 0.f, 0.f, 0.f};

#pragma unroll
  for (int ks = 0; ks < 8; ++ks) {
    const int kb = ks * 32 + lk8;
    bf16x8 a = *reinterpret_cast<const bf16x8*>(
        (const char*)zb + lr * 528 + kb * 2);
#pragma unroll
    for (int nt = 0; nt < 4; ++nt) {
      bf16x8 b = *reinterpret_cast<const bf16x8*>(
          wsrc + (size_t)(ncol0 + nt * 16 + lr) * 256 + kb);
      acc[nt] = __builtin_amdgcn_mfma_f32_16x16x32_bf16(a, b, acc[nt], 0, 0, 0);
    }
  }

  if (tile < E1TILES) {
    // tile == one 16-edge segment: reduce rows of relu(acc+bias)
#pragma unroll
    for (int nt = 0; nt < 4; ++nt) {
      const int col = ncol0 + nt * 16 + lr;
      const float bias = bs1[col];
      float v = 0.f;
#pragma unroll
      for (int q = 0; q < 4; ++q) v += fmaxf(acc[nt][q] + bias, 0.f);
      v += __shfl_xor(v, 16);
      v += __shfl_xor(v, 32);
      if (lane < 16) {
        agg1b[(size_t)tile * HID + col] = __float2bfloat16(v);
      }
    }
  } else {
    const int orow = (lane >> 4) * 4;
    const int rbase = tile * 16 - E1V;
#pragma unroll
    for (int nt = 0; nt < 4; ++nt) {
      const int col = ncol0 + nt * 16 + lr;
      const float bias = bs1[col];
#pragma unroll
      for (int q = 0; q < 4; ++q) {
        h1s[(size_t)(rbase + orow + q) * HID + col] =
            __float2bfloat16(fmaxf(acc[nt][q] + bias, 0.f));
      }
    }
  }
}

// K1: fused gather + gemm1, 2 tiles/block, software-pipelined.
// 1088 blocks x 256 thr (4 waves). Per tile: 16 nodes, 16 thr/node, thread
// owns float4 slots {c, c+16} of the 512B f32 row. Tile B's first load batch
// is issued BEFORE the lgkm-only barrier so it stays in flight under tile A's
// MFMA (loads cross s_barrier because we do NOT drain vmcnt).
__global__ __launch_bounds__(256, 3) void fused1_kernel(
    const float* __restrict__ x, const float* __restrict__ t2,
    const float* __restrict__ n_times2, const int* __restrict__ nodes2,
    const int* __restrict__ nbr2, const float* __restrict__ tk,
    const __hip_bfloat16* __restrict__ Wc1b, const float* __restrict__ bs1,
    __hip_bfloat16* __restrict__ agg1b, __hip_bfloat16* __restrict__ h1s) {
  __shared__ __hip_bfloat16 z[2][16][264];  // row stride 528B, 2 buffers
  const int t = threadIdx.x;
  const int r = t >> 4;
  const int c = t & 15;
  const int tileA = blockIdx.x * 2;
  const int tileB = tileA + 1;
  const int iA = tileA * 16 + r;
  const int iB = tileB * 16 + r;
  const float4* __restrict__ x4 = (const float4*)x;
  const float tkv = tk[0];
  const short* __restrict__ wsrc = (const short*)Wc1b;

  // ---- tile A: full gather + sums + LDS buf0 ----
  {
    const int4* nb4 = reinterpret_cast<const int4*>(nbr2) + iA * 4;
    int4 n0 = nb4[0], n1 = nb4[1], n2 = nb4[2], n3 = nb4[3];
    const int idx[16] = {n0.x, n0.y, n0.z, n0.w, n1.x, n1.y, n1.z, n1.w,
                         n2.x, n2.y, n2.z, n2.w, n3.x, n3.y, n3.z, n3.w};
    float4 s0 = {0.f, 0.f, 0.f, 0.f};
    float4 s1 = {0.f, 0.f, 0.f, 0.f};
#pragma unroll
    for (int k = 0; k < KFAN; ++k) {
      const float4* rp = x4 + (size_t)idx[k] * 32;
      float4 v0 = rp[c];
      float4 v1 = rp[16 + c];
      s0.x += v0.x; s0.y += v0.y; s0.z += v0.z; s0.w += v0.w;
      s1.x += v1.x; s1.y += v1.y; s1.z += v1.z; s1.w += v1.w;
    }
    const float dec = __expf(-tkv * (t2[iA] - n_times2[iA]));
    const float4* sp = x4 + (size_t)nodes2[iA] * 32;
    float4 u0 = sp[c];
    float4 u1 = sp[16 + c];

    char* zrow = (char*)&z[0][0][0] + r * 528;
    short4v p;
    p = (short4v){f2b(s0.x), f2b(s0.y), f2b(s0.z), f2b(s0.w)};
    *reinterpret_cast<short4v*>(zrow + c * 8) = p;
    p = (short4v){f2b(s1.x), f2b(s1.y), f2b(s1.z), f2b(s1.w)};
    *reinterpret_cast<short4v*>(zrow + 128 + c * 8) = p;
    p = (short4v){f2b(u0.x * dec), f2b(u0.y * dec), f2b(u0.z * dec), f2b(u0.w * dec)};
    *reinterpret_cast<short4v*>(zrow + 256 + c * 8) = p;
    p = (short4v){f2b(u1.x * dec), f2b(u1.y * dec), f2b(u1.z * dec), f2b(u1.w * dec)};
    *reinterpret_cast<short4v*>(zrow + 384 + c * 8) = p;
  }

  // ---- tile B: indices + ISSUE first load batch (slot c) + self ----
  int idxB[16];
  {
    const int4* nb4 = reinterpret_cast<const int4*>(nbr2) + iB * 4;
    int4 n0 = nb4[0], n1 = nb4[1], n2 = nb4[2], n3 = nb4[3];
    idxB[0] = n0.x; idxB[1] = n0.y; idxB[2]  = n0.z; idxB[3]  = n0.w;
    idxB[4] = n1.x; idxB[5] = n1.y; idxB[6]  = n1.z; idxB[7]  = n1.w;
    idxB[8] = n2.x; idxB[9] = n2.y; idxB[10] = n2.z; idxB[11] = n2.w;
    idxB[12] = n3.x; idxB[13] = n3.y; idxB[14] = n3.z; idxB[15] = n3.w;
  }
  float4 vB[16];
#pragma unroll
  for (int k = 0; k < KFAN; ++k)
    vB[k] = x4[(size_t)idxB[k] * 32 + c];   // slot c of each neighbor row
  const float4* spB = x4 + (size_t)nodes2[iB] * 32;
  float4 uB0 = spB[c];
  float4 uB1 = spB[16 + c];
  const float decB = __expf(-tkv * (t2[iB] - n_times2[iB]));

  // ---- lgkm-only barrier: drain LDS writes, let global loads stay in flight
  asm volatile("s_waitcnt lgkmcnt(0)" ::: "memory");
  __builtin_amdgcn_s_barrier();
  __builtin_amdgcn_sched_barrier(0);

  // ---- MFMA + epilogue tile A (tile B batch-1 loads arriving underneath) ----
  gemm_tile(&z[0][0][0], tileA, t, wsrc, bs1, agg1b, h1s);

  // ---- finish tile B: sum batch 1, issue+sum batch 2 (slot c+16), LDS buf1
  {
    float4 s0 = {0.f, 0.f, 0.f, 0.f};
#pragma unroll
    for (int k = 0; k < KFAN; ++k) {
      s0.x += vB[k].x; s0.y += vB[k].y; s0.z += vB[k].z; s0.w += vB[k].w;
    }
    float4 s1 = {0.f, 0.f, 0.f, 0.f};
#pragma unroll
    for (int k = 0; k < KFAN; ++k) {
      float4 v1 = x4[(size_t)idxB[k] * 32 + 16 + c];
      s1.x += v1.x; s1.y += v1.y; s1.z += v1.z; s1.w += v1.w;
    }

    char* zrow = (char*)&z[1][0][0] + r * 528;
    short4v p;
    p = (short4v){f2b(s0.x), f2b(s0.y), f2b(s0.z), f2b(s0.w)};
    *reinterpret_cast<short4v*>(zrow + c * 8) = p;
    p = (short4v){f2b(s1.x), f2b(s1.y), f2b(s1.z), f2b(s1.w)};
    *reinterpret_cast<short4v*>(zrow + 128 + c * 8) = p;
    p = (short4v){f2b(uB0.x * decB), f2b(uB0.y * decB), f2b(uB0.z * decB), f2b(uB0.w * decB)};
    *reinterpret_cast<short4v*>(zrow + 256 + c * 8) = p;
    p = (short4v){f2b(uB1.x * decB), f2b(uB1.y * decB), f2b(uB1.z * decB), f2b(uB1.w * decB)};
    *reinterpret_cast<short4v*>(zrow + 384 + c * 8) = p;
  }

  asm volatile("s_waitcnt lgkmcnt(0)" ::: "memory");
  __builtin_amdgcn_s_barrier();
  __builtin_amdgcn_sched_barrier(0);

  // ---- MFMA + epilogue tile B ----
  gemm_tile(&z[1][0][0], tileB, t, wsrc, bs1, agg1b, h1s);
}

// K2: layer2 via MFMA. 128 blocks x 1 wave; block = 16 batch rows x 128 cols,
// K = 512 ([agg1b | dec*h1s]), 8 nt x 16 ks. out f32.
__global__ __launch_bounds__(64) void layer2_kernel(
    const __hip_bfloat16* __restrict__ agg1b, const __hip_bfloat16* __restrict__ h1s,
    const float* __restrict__ ts, const float* __restrict__ n_times1,
    const float* __restrict__ tk, const __hip_bfloat16* __restrict__ Wc2b,
    const float* __restrict__ bs2, float* __restrict__ out) {
  const int lane = threadIdx.x;
  const int b0 = blockIdx.x * 16;
  const int lr = lane & 15;
  const int lk8 = (lane >> 4) * 8;
  const int row = b0 + lr;

  const float dec = __expf(-tk[0] * (ts[row] - n_times1[row]));
  const short* __restrict__ ag = (const short*)agg1b;
  const short* __restrict__ hs = (const short*)h1s;
  const short* __restrict__ w2 = (const short*)Wc2b;

  f32x4 acc[8];
#pragma unroll
  for (int n = 0; n < 8; ++n) acc[n] = (f32x4){0.f, 0.f, 0.f, 0.f};

#pragma unroll
  for (int ks = 0; ks < 16; ++ks) {
    const int kb = ks * 32 + lk8;
    bf16x8 a;
    if (kb < HID) {
      a = *reinterpret_cast<const bf16x8*>(ag + (size_t)row * HID + kb);
    } else {
      bf16x8 hv = *reinterpret_cast<const bf16x8*>(hs + (size_t)row * HID + (kb - HID));
#pragma unroll
      for (int e = 0; e < 8; ++e) a[e] = f2b(bf2f(hv[e]) * dec);
    }
#pragma unroll
    for (int nt = 0; nt < 8; ++nt) {
      bf16x8 b = *reinterpret_cast<const bf16x8*>(
          w2 + (size_t)(nt * 16 + lr) * 512 + kb);
      acc[nt] = __builtin_amdgcn_mfma_f32_16x16x32_bf16(a, b, acc[nt], 0, 0, 0);
    }
  }

  const int orow = (lane >> 4) * 4;
#pragma unroll
  for (int nt = 0; nt < 8; ++nt) {
    const int col = nt * 16 + lr;
    const float bias = bs2[col];
#pragma unroll
    for (int q = 0; q < 4; ++q) {
      out[(size_t)(b0 + orow + q) * OUTD + col] = fmaxf(acc[nt][q] + bias, 0.f);
    }
  }
}

extern "C" void kernel_launch(void* const* d_in, const int* in_sizes, int n_in,
                              void* d_out, int out_size, void* d_ws, size_t ws_size,
                              hipStream_t stream) {
  const float* x        = (const float*)d_in[0];
  const float* ts       = (const float*)d_in[1];
  const float* t2       = (const float*)d_in[2];
  const float* n_times1 = (const float*)d_in[3];
  const float* n_times2 = (const float*)d_in[4];
  const float* W1n      = (const float*)d_in[5];
  const float* b1n      = (const float*)d_in[6];
  const float* W1h      = (const float*)d_in[7];
  const float* b1h      = (const float*)d_in[8];
  const float* W2n      = (const float*)d_in[9];
  const float* b2n      = (const float*)d_in[10];
  const float* W2h      = (const float*)d_in[11];
  const float* b2h      = (const float*)d_in[12];
  const float* tk       = (const float*)d_in[13];
  const int*   nodes2   = (const int*)d_in[14];
  const int*   nbr2     = (const int*)d_in[15];
  // d_in[16] = seg2, d_in[17] = seg1 — implicit (row-major repeat layout)

  float* ws = (float*)d_ws;
  float* bs1 = ws + OFF_BS1;
  float* bs2 = ws + OFF_BS2;
  __hip_bfloat16* Wc1b  = (__hip_bfloat16*)(ws + OFF_WC1B);
  __hip_bfloat16* Wc2b  = (__hip_bfloat16*)(ws + OFF_WC2B);
  __hip_bfloat16* agg1b = (__hip_bfloat16*)(ws + OFF_AGG1B);
  __hip_bfloat16* h1s   = (__hip_bfloat16*)(ws + OFF_H1S);
  float* out = (float*)d_out;

  prepack_kernel<<<256, 256, 0, stream>>>(W1n, b1n, W1h, b1h,
                                          W2n, b2n, W2h, b2h,
                                          Wc1b, Wc2b, bs1, bs2);
  fused1_kernel<<<N2V / 32, 256, 0, stream>>>(x, t2, n_times2, nodes2, nbr2, tk,
                                              Wc1b, bs1, agg1b, h1s);
  layer2_kernel<<<BATCH / 16, 64, 0, stream>>>(agg1b, h1s, ts, n_times1, tk,
                                               Wc2b, bs2, out);
}